// Round 9
// baseline (50693.024 us; speedup 1.0000x reference)
//
#include <hip/hip_runtime.h>
#include <math.h>

constexpr int B    = 512;
constexpr int T    = 64;
constexpr int H    = 512;
constexpr int V    = 780;
constexpr int N_AT = 40;
constexpr int KC   = 4;
constexpr int NB   = 8;
constexpr int BT   = B * T;      // 32768
constexpr int NMSG = BT + 1;     // 32769
constexpr int BH   = B * H;      // 262144
constexpr int NBLK = 256;        // persistent grid size (1 block/CU)

__device__ __forceinline__ float sigf(float x) { return 1.f / (1.f + expf(-x)); }

// Manual device-wide barrier: monotonic counter, agent-scope atomics.
// Release on arrive (prior writes visible), acquire on exit (peer writes visible).
__device__ __forceinline__ void gbar(unsigned* cnt, unsigned& epoch)
{
    __syncthreads();
    if (threadIdx.x == 0) {
        epoch += NBLK;
        __hip_atomic_fetch_add(cnt, 1u, __ATOMIC_RELEASE, __HIP_MEMORY_SCOPE_AGENT);
        while (__hip_atomic_load(cnt, __ATOMIC_ACQUIRE, __HIP_MEMORY_SCOPE_AGENT) < epoch)
            __builtin_amdgcn_s_sleep(1);
    }
    __syncthreads();
}

// ===========================================================================
// Phase bodies (verified in round 8)
// ===========================================================================

// z/h dual GEMM, 128 blocks of 32x64 tiles. K=1024 (seg0 x, seg1 sumh/sumg).
// table[b*T+t+1] = (1-z)*sumh + z*tanh-preh
__device__ __forceinline__ void ph_zh(int t, int bx, int tid,
    float* As1, float* As2, float* W1s, float* W2s,
    const float* __restrict__ xb, const float* __restrict__ sumh,
    const float* __restrict__ sumg,
    const float* __restrict__ Wz, const float* __restrict__ bz,
    const float* __restrict__ Wh, const float* __restrict__ bh,
    float* __restrict__ table)
{
    const int rt = bx >> 3, ct = bx & 7, row0 = rt * 32, col0 = ct * 64;
    const int tm = tid >> 4, tn = tid & 15;
    const int ak = tid & 31, am0 = tid >> 5, wn = tid & 63, wk0 = tid >> 6;
    float az[2][4] = {}, ah[2][4] = {};

    // seg0: shared A = x
    for (int k0 = 0; k0 < H; k0 += 32) {
#pragma unroll
        for (int it = 0; it < 4; ++it) {
            const int m = am0 + it * 8;
            As1[ak * 38 + m] = xb[(size_t)(row0 + m) * H + k0 + ak];
        }
#pragma unroll
        for (int it = 0; it < 8; ++it) {
            const int kk = wk0 + it * 4;
            W1s[kk * 68 + wn] = Wz[(size_t)(k0 + kk) * H + col0 + wn];
            W2s[kk * 68 + wn] = Wh[(size_t)(k0 + kk) * H + col0 + wn];
        }
        __syncthreads();
#pragma unroll
        for (int kk = 0; kk < 32; ++kk) {
            const float a0 = As1[kk * 38 + tm * 2];
            const float a1 = As1[kk * 38 + tm * 2 + 1];
            float w1[4], w2[4];
            *(float4*)w1 = *(const float4*)&W1s[kk * 68 + tn * 4];
            *(float4*)w2 = *(const float4*)&W2s[kk * 68 + tn * 4];
#pragma unroll
            for (int j = 0; j < 4; ++j) {
                az[0][j] = fmaf(a0, w1[j], az[0][j]);
                az[1][j] = fmaf(a1, w1[j], az[1][j]);
                ah[0][j] = fmaf(a0, w2[j], ah[0][j]);
                ah[1][j] = fmaf(a1, w2[j], ah[1][j]);
            }
        }
        __syncthreads();
    }
    // seg1: A1 = sumh -> z, A2 = sumg -> h
    for (int k0 = 0; k0 < H; k0 += 32) {
#pragma unroll
        for (int it = 0; it < 4; ++it) {
            const int m = am0 + it * 8;
            As1[ak * 38 + m] = sumh[(size_t)(row0 + m) * H + k0 + ak];
            As2[ak * 38 + m] = sumg[(size_t)(row0 + m) * H + k0 + ak];
        }
#pragma unroll
        for (int it = 0; it < 8; ++it) {
            const int kk = wk0 + it * 4;
            W1s[kk * 68 + wn] = Wz[(size_t)(H + k0 + kk) * H + col0 + wn];
            W2s[kk * 68 + wn] = Wh[(size_t)(H + k0 + kk) * H + col0 + wn];
        }
        __syncthreads();
#pragma unroll
        for (int kk = 0; kk < 32; ++kk) {
            const float a10 = As1[kk * 38 + tm * 2];
            const float a11 = As1[kk * 38 + tm * 2 + 1];
            const float a20 = As2[kk * 38 + tm * 2];
            const float a21 = As2[kk * 38 + tm * 2 + 1];
            float w1[4], w2[4];
            *(float4*)w1 = *(const float4*)&W1s[kk * 68 + tn * 4];
            *(float4*)w2 = *(const float4*)&W2s[kk * 68 + tn * 4];
#pragma unroll
            for (int j = 0; j < 4; ++j) {
                az[0][j] = fmaf(a10, w1[j], az[0][j]);
                az[1][j] = fmaf(a11, w1[j], az[1][j]);
                ah[0][j] = fmaf(a20, w2[j], ah[0][j]);
                ah[1][j] = fmaf(a21, w2[j], ah[1][j]);
            }
        }
        __syncthreads();
    }
    // epilogue: GRU blend -> table row b*T+t+1
#pragma unroll
    for (int i = 0; i < 2; ++i) {
        const int b = row0 + tm * 2 + i;
        const float4 s4 = *(const float4*)&sumh[(size_t)b * H + col0 + tn * 4];
        const float sv[4] = {s4.x, s4.y, s4.z, s4.w};
        float out[4];
#pragma unroll
        for (int j = 0; j < 4; ++j) {
            const int c = col0 + tn * 4 + j;
            const float z  = sigf(az[i][j] + bz[c]);
            const float ph = tanhf(ah[i][j] + bh[c]);
            out[j] = (1.f - z) * sv[j] + z * ph;
        }
        *(float4*)&table[((size_t)b * T + t + 1) * H + col0 + tn * 4] = *(float4*)out;
    }
}

// Generic 32x64-tile GEMM over K=512.
// AS: 0 = A[m][k] plain | 1 = A/C row = (m*T + tpos) | 2 = masked table gather
template<int AS>
__device__ __forceinline__ void tile_g(int bx, int tid, float* As, float* Ws_,
    const float* __restrict__ Abase, int tpos,
    const int* __restrict__ nh, int tstep,
    const float* __restrict__ W, const float* __restrict__ bias,
    float* __restrict__ C)
{
    const int rt = bx >> 3, ct = bx & 7, row0 = rt * 32, col0 = ct * 64;
    const int tm = tid >> 4, tn = tid & 15;
    const int ak = tid & 31, am0 = tid >> 5, wn = tid & 63, wk0 = tid >> 6;
    float ac[2][4] = {};

    for (int k0 = 0; k0 < H; k0 += 32) {
#pragma unroll
        for (int it = 0; it < 4; ++it) {
            const int m = am0 + it * 8, gm = row0 + m;
            float v;
            if (AS == 0) {
                v = Abase[(size_t)gm * H + k0 + ak];
            } else if (AS == 1) {
                v = Abase[((size_t)gm * T + tpos) * H + k0 + ak];
            } else {
                const int b = gm >> 3, n = gm & 7;
                const int gi = nh[((size_t)b * T + tstep) * NB + n];
                v = (gi != 0 && ((gi - 1) & 63) == tstep)
                        ? 0.f : Abase[(size_t)gi * H + k0 + ak];
            }
            As[ak * 38 + m] = v;
        }
#pragma unroll
        for (int it = 0; it < 8; ++it) {
            const int kk = wk0 + it * 4;
            Ws_[kk * 68 + wn] = W[(size_t)(k0 + kk) * H + col0 + wn];
        }
        __syncthreads();
#pragma unroll
        for (int kk = 0; kk < 32; ++kk) {
            const float a0 = As[kk * 38 + tm * 2];
            const float a1 = As[kk * 38 + tm * 2 + 1];
            float w[4];
            *(float4*)w = *(const float4*)&Ws_[kk * 68 + tn * 4];
#pragma unroll
            for (int j = 0; j < 4; ++j) {
                ac[0][j] = fmaf(a0, w[j], ac[0][j]);
                ac[1][j] = fmaf(a1, w[j], ac[1][j]);
            }
        }
        __syncthreads();
    }
#pragma unroll
    for (int i = 0; i < 2; ++i) {
        const int gm = row0 + tm * 2 + i;
        float out[4];
#pragma unroll
        for (int j = 0; j < 4; ++j)
            out[j] = ac[i][j] + (bias ? bias[col0 + tn * 4 + j] : 0.f);
        float* dst = (AS == 1) ? &C[((size_t)gm * T + tpos) * H + col0 + tn * 4]
                               : &C[(size_t)gm * H + col0 + tn * 4];
        *(float4*)dst = *(float4*)out;
    }
}

// clique gather: xb[b][h4..] for step tg (one float4 unit)
__device__ __forceinline__ void ph_xgather(int tg, int unit,
    const float* __restrict__ node_rep, const int* __restrict__ cliq,
    float* __restrict__ xb)
{
    const int b = unit >> 7, h4 = (unit & 127) * 4;
    const int* ci = cliq + ((size_t)b * T + tg) * KC;
    float4 s = {0.f, 0.f, 0.f, 0.f};
#pragma unroll
    for (int j = 0; j < KC; ++j) {
        const float4 v = *(const float4*)&node_rep[((size_t)b * N_AT + ci[j]) * H + h4];
        s.x += v.x; s.y += v.y; s.z += v.z; s.w += v.w;
    }
    *(float4*)&xb[(size_t)b * H + h4] = s;
}

// masked sumh / sumg gathers for step tg
template<bool USETU>
__device__ __forceinline__ void ph_sums(int tg, int unit,
    const int* __restrict__ nh, const float* __restrict__ xr,
    const float* __restrict__ table, const float* __restrict__ tu,
    const float* __restrict__ hU,
    float* __restrict__ sumh, float* __restrict__ sumg)
{
    const int b = unit >> 7, h4 = (unit & 127) * 4;
    const int* hi = nh + ((size_t)b * T + tg) * NB;
    const float4 x4 = *(const float4*)&xr[(size_t)b * H + h4];
    float4 sh = {0.f, 0.f, 0.f, 0.f}, sg = {0.f, 0.f, 0.f, 0.f};
#pragma unroll
    for (int n = 0; n < NB; ++n) {
        const int idx = hi[n];
        float4 hv = {0.f, 0.f, 0.f, 0.f};
        if (!(idx != 0 && ((idx - 1) & 63) == tg))
            hv = *(const float4*)&table[(size_t)idx * H + h4];
        const float4 hu = USETU ? *(const float4*)&tu[(size_t)idx * H + h4]
                                : *(const float4*)&hU[((size_t)b * NB + n) * H + h4];
        sh.x += hv.x; sh.y += hv.y; sh.z += hv.z; sh.w += hv.w;
        sg.x += hv.x * sigf(x4.x + hu.x);
        sg.y += hv.y * sigf(x4.y + hu.y);
        sg.z += hv.z * sigf(x4.z + hu.z);
        sg.w += hv.w * sigf(x4.w + hu.w);
    }
    *(float4*)&sumh[(size_t)b * H + h4] = sh;
    *(float4*)&sumg[(size_t)b * H + h4] = sg;
}

// ===========================================================================
// Persistent loop: normal launch, 256 blocks x 256 threads, manual barriers
// ===========================================================================
template<bool USETU>
__global__ __launch_bounds__(256)
void loop_k(const int* __restrict__ nei_h, const float* __restrict__ node_rep,
            const int* __restrict__ cliq,
            const float* __restrict__ Wz, const float* __restrict__ bz,
            const float* __restrict__ Wh, const float* __restrict__ bh,
            const float* __restrict__ Ur, const float* __restrict__ Wr,
            const float* __restrict__ br,
            float* table, float* tu, float* hU,
            float* xb0, float* xb1, float* xrb, float* sumh, float* sumg,
            unsigned* barcnt)
{
    __shared__ float As1[32 * 38], As2[32 * 38], W1s[32 * 68], W2s[32 * 68];
    const int bid = blockIdx.x, tid = threadIdx.x;
    unsigned epoch = 0;

    for (int t = 0; t < T; ++t) {
        float* xbc = (t & 1) ? xb1 : xb0;
        float* xbn = (t & 1) ? xb0 : xb1;
        // Phase A: z/h GEMM(t)  ||  x gather(t+1)
        if (bid < 128) {
            ph_zh(t, bid, tid, As1, As2, W1s, W2s, xbc, sumh, sumg,
                  Wz, bz, Wh, bh, table);
        } else if (t + 1 < T) {
            const int base = (bid - 128) * 512 + tid;
            ph_xgather(t + 1, base,       node_rep, cliq, xbn);
            ph_xgather(t + 1, base + 256, node_rep, cliq, xbn);
        }
        if (t + 1 == T) break;
        gbar(barcnt, epoch);
        // Phase B: tableU(t+1) (or hU(t+1))  ||  xr GEMM(t+1)
        if (USETU) {
            if (bid < 128)
                tile_g<1>(bid, tid, As1, W1s, table, t + 1, nullptr, 0,
                          Ur, nullptr, tu);
            else
                tile_g<0>(bid - 128, tid, As1, W1s, xbn, 0, nullptr, 0,
                          Wr, br, xrb);
        } else {
#pragma unroll
            for (int q = 0; q < 4; ++q)
                tile_g<2>(bid * 4 + q, tid, As1, W1s, table, 0, nei_h, t + 1,
                          Ur, nullptr, hU);
            if (bid < 128)
                tile_g<0>(bid, tid, As1, W1s, xbn, 0, nullptr, 0, Wr, br, xrb);
        }
        gbar(barcnt, epoch);
        // Phase C: masked sums(t+1)
        ph_sums<USETU>(t + 1, bid * 256 + tid, nei_h, xrb, table, tu, hU,
                       sumh, sumg);
        gbar(barcnt, epoch);
    }
}

// pre-loop x gather for t=0
__global__ __launch_bounds__(256)
void xg0_k(const float* __restrict__ node_rep, const int* __restrict__ cliq,
           float* __restrict__ xb)
{
    ph_xgather(0, blockIdx.x * 256 + threadIdx.x, node_rep, cliq, xb);
}

// ===========================================================================
// Post-loop: o_all from FINAL table with step mask ((idx-1)&63 < t)
// ===========================================================================
__global__ __launch_bounds__(256)
void oall_k(const int* __restrict__ nei_o, const float* __restrict__ table,
            float* __restrict__ o_all)
{
    const int i = blockIdx.x * 256 + threadIdx.x;   // BT*H/4
    const int m = i >> 7, h4 = (i & 127) * 4;       // m = b*T + t
    const int t = m & 63;
    const int* oi = nei_o + (size_t)m * NB;
    float4 s = {0.f, 0.f, 0.f, 0.f};
#pragma unroll
    for (int n = 0; n < NB; ++n) {
        const int idx = oi[n];
        if (idx != 0 && ((idx - 1) & 63) < t) {
            const float4 hv = *(const float4*)&table[(size_t)idx * H + h4];
            s.x += hv.x; s.y += hv.y; s.z += hv.z; s.w += hv.w;
        }
    }
    *(float4*)&o_all[(size_t)m * H + h4] = s;
}

// ===========================================================================
// Heads (verified round 8)
// ASRC: 0 plain | 3 stop (A2=o_all) | 7 stop (inline masked-o from table)
// EPI: 3 relu | 4 relu*Usw partial
// ===========================================================================
constexpr size_t SM_GEMM = (size_t)(2 * 32 * 68) * 4;
constexpr size_t SM_STOP = (size_t)(2 * 32 * 68 + 64 * 17) * 4;

template<int ASRC, int NSEG, int EPI>
__global__ __launch_bounds__(256)
void gemm_g(const float* __restrict__ A1, const float* __restrict__ A2, int lda,
            const float* __restrict__ W, const float* __restrict__ bias,
            float* __restrict__ C, int ldc,
            const float* __restrict__ node_rep, const int* __restrict__ cliq,
            const int* __restrict__ rci, const int* __restrict__ rni,
            const int* __restrict__ neio, const float* __restrict__ table,
            const float* __restrict__ Usw, float* __restrict__ partial)
{
    extern __shared__ float smem[];
    float* As = smem;
    float* Ws = smem + 32 * 68;
    const int tid = threadIdx.x, row0 = blockIdx.x * 64, col0 = blockIdx.y * 64;
    const int tm = tid >> 4, tn = tid & 15;
    const int ar0 = tid >> 5, ac = tid & 31, wk0 = tid >> 6, wc = tid & 63;
    float acc[4][4] = {};

    for (int seg = 0; seg < NSEG; ++seg) {
        const float* Wseg = W + (size_t)seg * H * H;
        for (int k0 = 0; k0 < H; k0 += 32) {
#pragma unroll
            for (int it = 0; it < 8; ++it) {
                const int r = ar0 + it * 8, grow = row0 + r;
                float v;
                if (ASRC == 0) {
                    v = A1[(size_t)grow * lda + k0 + ac];
                } else {
                    if (grow < BT) {
                        if (seg == 0) {
                            const int* ci = cliq + (size_t)grow * KC;
                            const int b = grow >> 6;
                            v = 0.f;
#pragma unroll
                            for (int j = 0; j < KC; ++j)
                                v += node_rep[((size_t)b * N_AT + ci[j]) * H + k0 + ac];
                        } else if (ASRC == 3) {
                            v = A2[(size_t)grow * H + k0 + ac];
                        } else {  // ASRC == 7: inline masked o
                            const int tt = grow & 63;
                            const int* oi = neio + (size_t)grow * NB;
                            v = 0.f;
#pragma unroll
                            for (int n = 0; n < NB; ++n) {
                                const int idx = oi[n];
                                if (idx != 0 && ((idx - 1) & 63) < tt)
                                    v += table[(size_t)idx * H + k0 + ac];
                            }
                        }
                    } else {
                        const int b = grow - BT;
                        v = 0.f;
                        if (seg == 0) {
#pragma unroll
                            for (int j = 0; j < KC; ++j)
                                v += node_rep[((size_t)b * N_AT + rci[b * KC + j]) * H + k0 + ac];
                        } else {
#pragma unroll
                            for (int n = 0; n < NB; ++n)
                                v += table[(size_t)rni[b * NB + n] * H + k0 + ac];
                        }
                    }
                }
                As[(size_t)ac * 68 + r] = v;
                const int kk = wk0 + it * 4;
                Ws[(size_t)kk * 68 + wc] = Wseg[(size_t)(k0 + kk) * H + col0 + wc];
            }
            __syncthreads();
#pragma unroll
            for (int kk = 0; kk < 32; ++kk) {
                float a[4], w[4];
                *(float4*)a = *(const float4*)&As[kk * 68 + tm * 4];
                *(float4*)w = *(const float4*)&Ws[kk * 68 + tn * 4];
#pragma unroll
                for (int i = 0; i < 4; ++i)
#pragma unroll
                    for (int j = 0; j < 4; ++j)
                        acc[i][j] = fmaf(a[i], w[j], acc[i][j]);
            }
            __syncthreads();
        }
    }

    if (EPI == 4) {
        float* sred = smem + 2 * 32 * 68;   // [64][17]
#pragma unroll
        for (int i = 0; i < 4; ++i) {
            float s = 0.f;
#pragma unroll
            for (int j = 0; j < 4; ++j) {
                const int c = col0 + tn * 4 + j;
                s += fmaxf(acc[i][j] + bias[c], 0.f) * Usw[c];
            }
            sred[(size_t)(tm * 4 + i) * 17 + tn] = s;
        }
        __syncthreads();
        if (tid < 64) {
            float s = 0.f;
#pragma unroll
            for (int q = 0; q < 16; ++q) s += sred[(size_t)tid * 17 + q];
            partial[(size_t)(row0 + tid) * 8 + blockIdx.y] = s;
        }
    } else {
#pragma unroll
        for (int i = 0; i < 4; ++i) {
            const int r = row0 + tm * 4 + i;
            float out[4];
#pragma unroll
            for (int j = 0; j < 4; ++j) {
                float val = acc[i][j] + (bias ? bias[col0 + tn * 4 + j] : 0.f);
                if (EPI == 3) val = fmaxf(val, 0.f);
                out[j] = val;
            }
            *(float4*)&C[(size_t)r * ldc + col0 + tn * 4] = *(float4*)out;
        }
    }
}

__global__ __launch_bounds__(256)
void stopfin_kernel(const float* __restrict__ partial, const float* __restrict__ Usb,
                    const int* __restrict__ direction, float* __restrict__ accum)
{
    const int i = blockIdx.x * 256 + threadIdx.x;   // BT+B exactly
    float loss = 0.f, acc = 0.f;
    {
        float s = Usb[0];
#pragma unroll
        for (int cb = 0; cb < 8; ++cb) s += partial[(size_t)i * 8 + cb];
        const float tgt = (i < BT) ? (float)direction[i] : 0.f;
        loss = fmaxf(s, 0.f) - s * tgt + log1pf(expf(-fabsf(s)));
        const float p = (s >= 0.f) ? 1.f : 0.f;
        acc = (p == tgt) ? 1.f : 0.f;
    }
#pragma unroll
    for (int off = 32; off; off >>= 1) {
        loss += __shfl_down(loss, off);
        acc  += __shfl_down(acc, off);
    }
    if ((threadIdx.x & 63) == 0) {
        atomicAdd(&accum[3], loss);
        atomicAdd(&accum[4], acc);
    }
}

// pred head phase 2: fused scores GEMM + log-softmax CE + argmax (verified)
__global__ __launch_bounds__(256)
void ce_kernel(const float* __restrict__ s1_all, const float* __restrict__ Wo,
               const float* __restrict__ Wob, const int* __restrict__ direction,
               const int* __restrict__ ptgt, float* __restrict__ accum)
{
    __shared__ float s1T[512 * 34];
    __shared__ float Ws[32 * 68];
    __shared__ float blk[3];
    const int tid  = threadIdx.x;
    const int row0 = blockIdx.x * 32;

    for (int idx = tid; idx < 32 * 512; idx += 256) {
        const int r = idx >> 9, k = idx & 511;
        s1T[(size_t)k * 34 + r] = s1_all[(size_t)(row0 + r) * H + k];
    }
    if (tid < 3) blk[tid] = 0.f;
    __syncthreads();

    const int tm = tid >> 4, tn = tid & 15;
    const int tgt0 = ptgt[row0 + tm * 2];
    const int tgt1 = ptgt[row0 + tm * 2 + 1];
    float m0 = -1e30f, m1 = -1e30f, ss0 = 0.f, ss1 = 0.f, st0 = 0.f, st1 = 0.f;
    float bv0 = -1e30f, bv1 = -1e30f;
    int   bj0 = 0, bj1 = 0;

    for (int ct = 0; ct < 13; ++ct) {
        const int col0 = ct * 64;
        float acc[2][4] = {};
        for (int k0 = 0; k0 < 512; k0 += 32) {
#pragma unroll
            for (int it = 0; it < 8; ++it) {
                const int idx = tid + it * 256;
                const int kk = idx >> 6, cc = idx & 63;
                const int col = col0 + cc;
                Ws[(size_t)kk * 68 + cc] = (col < V) ? Wo[(size_t)(k0 + kk) * V + col] : 0.f;
            }
            __syncthreads();
#pragma unroll
            for (int kk = 0; kk < 32; ++kk) {
                const float a0 = s1T[(size_t)(k0 + kk) * 34 + tm * 2];
                const float a1 = s1T[(size_t)(k0 + kk) * 34 + tm * 2 + 1];
                float w[4];
                *(float4*)w = *(const float4*)&Ws[kk * 68 + tn * 4];
#pragma unroll
                for (int j = 0; j < 4; ++j) {
                    acc[0][j] = fmaf(a0, w[j], acc[0][j]);
                    acc[1][j] = fmaf(a1, w[j], acc[1][j]);
                }
            }
            __syncthreads();
        }
#pragma unroll
        for (int j = 0; j < 4; ++j) {
            const int col = col0 + tn * 4 + j;
            if (col < V) {
                const float wb  = Wob[col];
                const float sc0 = acc[0][j] + wb;
                const float sc1 = acc[1][j] + wb;
                if (sc0 > m0) { ss0 = ss0 * expf(m0 - sc0) + 1.f; m0 = sc0; }
                else          { ss0 += expf(sc0 - m0); }
                if (sc1 > m1) { ss1 = ss1 * expf(m1 - sc1) + 1.f; m1 = sc1; }
                else          { ss1 += expf(sc1 - m1); }
                if (sc0 > bv0) { bv0 = sc0; bj0 = col; }
                if (sc1 > bv1) { bv1 = sc1; bj1 = col; }
                if (col == tgt0) st0 = sc0;
                if (col == tgt1) st1 = sc1;
            }
        }
    }

#pragma unroll
    for (int off = 1; off < 16; off <<= 1) {
        float om, os;
        om = __shfl_xor(m0, off); os = __shfl_xor(ss0, off);
        { const float nm = fmaxf(m0, om); ss0 = ss0 * expf(m0 - nm) + os * expf(om - nm); m0 = nm; }
        om = __shfl_xor(m1, off); os = __shfl_xor(ss1, off);
        { const float nm = fmaxf(m1, om); ss1 = ss1 * expf(m1 - nm) + os * expf(om - nm); m1 = nm; }
        float obv; int obj;
        obv = __shfl_xor(bv0, off); obj = __shfl_xor(bj0, off);
        if (obv > bv0 || (obv == bv0 && obj < bj0)) { bv0 = obv; bj0 = obj; }
        obv = __shfl_xor(bv1, off); obj = __shfl_xor(bj1, off);
        if (obv > bv1 || (obv == bv1 && obj < bj1)) { bv1 = obv; bj1 = obj; }
        st0 += __shfl_xor(st0, off);
        st1 += __shfl_xor(st1, off);
    }
    if (tn == 0) {
        float ce_s = 0.f, cnt = 0.f, corr = 0.f;
        {
            const int row = row0 + tm * 2;
            if (direction[row] == 1) {
                ce_s += (m0 + logf(ss0)) - st0; cnt += 1.f;
                corr += (bj0 == tgt0) ? 1.f : 0.f;
            }
        }
        {
            const int row = row0 + tm * 2 + 1;
            if (direction[row] == 1) {
                ce_s += (m1 + logf(ss1)) - st1; cnt += 1.f;
                corr += (bj1 == tgt1) ? 1.f : 0.f;
            }
        }
        atomicAdd(&blk[0], ce_s); atomicAdd(&blk[1], cnt); atomicAdd(&blk[2], corr);
    }
    __syncthreads();
    if (tid == 0) {
        atomicAdd(&accum[0], blk[0]);
        atomicAdd(&accum[1], blk[1]);
        atomicAdd(&accum[2], blk[2]);
    }
}

// no-tableU fallback pred head (round-0 proven; reads table directly)
constexpr int PH_ROWS = 8;
__global__ __launch_bounds__(256)
void predhead_kernel(const float* __restrict__ table,
                     const float* __restrict__ Ww, const float* __restrict__ Wb,
                     const float* __restrict__ Wo, const float* __restrict__ Wob,
                     const int* __restrict__ direction, const int* __restrict__ ptgt,
                     float* __restrict__ accum)
{
    __shared__ float hs[PH_ROWS][520];
    __shared__ float s1s[PH_ROWS][520];
    const int row0 = blockIdx.x * PH_ROWS;
    const int tid  = threadIdx.x;
    for (int i = tid; i < PH_ROWS * H; i += 256) {
        const int r = i >> 9, c = i & 511;
        hs[r][c] = table[(size_t)(row0 + r + 1) * H + c];
    }
    __syncthreads();
    const int r  = tid >> 5;
    const int tx = tid & 31;
    for (int j = 0; j < 16; ++j) {
        const int c = tx + j * 32;
        float acc = Wb[c];
        for (int k = 0; k < H; ++k) acc += hs[r][k] * Ww[(size_t)k * H + c];
        s1s[r][c] = fmaxf(acc, 0.f);
    }
    __syncthreads();
    const int row = row0 + r;
    const int tgt = ptgt[row];
    float m = -1e30f, ssum = 0.f, stgt = 0.f;
    float bestv = -1e30f; int bestj = 0;
    for (int v = tx; v < V; v += 32) {
        float sc = Wob[v];
        const float* wcol = Wo + v;
        for (int k = 0; k < H; ++k) sc += s1s[r][k] * wcol[(size_t)k * V];
        if (sc > m) { ssum = ssum * expf(m - sc) + 1.f; m = sc; }
        else        { ssum += expf(sc - m); }
        if (sc > bestv) { bestv = sc; bestj = v; }
        if (v == tgt) stgt = sc;
    }
#pragma unroll
    for (int off = 1; off < 32; off <<= 1) {
        const float om = __shfl_xor(m, off);
        const float os = __shfl_xor(ssum, off);
        const float nm = fmaxf(m, om);
        ssum = ssum * expf(m - nm) + os * expf(om - nm);
        m = nm;
        const float obv = __shfl_xor(bestv, off);
        const int   obj = __shfl_xor(bestj, off);
        if (obv > bestv || (obv == bestv && obj < bestj)) { bestv = obv; bestj = obj; }
        stgt += __shfl_xor(stgt, off);
    }
    if (tx == 0) {
        const float ce   = (m + logf(ssum)) - stgt;
        const float mask = (direction[row] == 1) ? 1.f : 0.f;
        const float corr = (bestj == tgt) ? 1.f : 0.f;
        atomicAdd(&accum[0], ce * mask);
        atomicAdd(&accum[1], mask);
        atomicAdd(&accum[2], corr * mask);
    }
}

__global__ void finalize_kernel(const float* __restrict__ accum, float* __restrict__ out)
{
    if (threadIdx.x == 0) {
        out[0] = accum[0] / (float)B;
        out[1] = accum[3] / (float)B;
        out[2] = accum[2] / accum[1];
        out[3] = accum[4] / (float)(BT + B);
    }
}

// ===========================================================================
extern "C" void kernel_launch(void* const* d_in, const int* in_sizes, int n_in,
                              void* d_out, int out_size, void* d_ws, size_t ws_size,
                              hipStream_t stream)
{
    (void)in_sizes; (void)n_in; (void)out_size;

    const float* node_rep        = (const float*)d_in[0];
    const int*   clique_idx      = (const int*)d_in[1];
    const int*   root_clique_idx = (const int*)d_in[2];
    const int*   nei_h_idx       = (const int*)d_in[3];
    const int*   nei_o_idx       = (const int*)d_in[4];
    const int*   root_nei_idx    = (const int*)d_in[5];
    const int*   direction       = (const int*)d_in[6];
    const int*   pred_target     = (const int*)d_in[7];
    const float* W_z_w = (const float*)d_in[8];
    const float* W_z_b = (const float*)d_in[9];
    const float* W_r_w = (const float*)d_in[10];
    const float* W_r_b = (const float*)d_in[11];
    const float* U_r_w = (const float*)d_in[12];
    const float* W_h_w = (const float*)d_in[13];
    const float* W_h_b = (const float*)d_in[14];
    const float* W_w   = (const float*)d_in[15];
    const float* W_b   = (const float*)d_in[16];
    const float* U_w   = (const float*)d_in[17];
    const float* U_b   = (const float*)d_in[18];
    const float* W_o_w = (const float*)d_in[19];
    const float* W_o_b = (const float*)d_in[20];
    const float* U_s_w = (const float*)d_in[21];
    const float* U_s_b = (const float*)d_in[22];

    float* ws = (float*)d_ws;
    const size_t availF = ws_size / sizeof(float);
    size_t off = 0;
    auto alloc = [&](size_t n) { float* p = ws + off; off += n; return p; };

    float* table   = alloc((size_t)NMSG * H);
    float* xb0     = alloc(BH);
    float* xb1     = alloc(BH);
    float* xrb     = alloc(BH);
    float* sumh    = alloc(BH);
    float* sumg    = alloc(BH);
    float* partial = alloc((size_t)(BT + B) * 8);
    float* accum   = alloc(16);                 // [0..7] accum, [8] barrier cnt
    unsigned* barcnt = (unsigned*)(accum + 8);

    // gate the 67 MB tableU on actual ws capacity (proven: ws >= 152.3 MB)
    float* tu = nullptr;
    float* hU = nullptr;
    if (off + (size_t)NMSG * H <= availF) tu = alloc((size_t)NMSG * H);
    else                                  hU = alloc((size_t)B * NB * H);

    hipMemsetAsync(table, 0, (size_t)NMSG * H * sizeof(float), stream);
    if (tu) hipMemsetAsync(tu, 0, (size_t)NMSG * H * sizeof(float), stream);
    hipMemsetAsync(sumh, 0, (size_t)BH * sizeof(float), stream);
    hipMemsetAsync(sumg, 0, (size_t)BH * sizeof(float), stream);
    hipMemsetAsync(accum, 0, 16 * sizeof(float), stream);

    // pre-loop: x for t=0
    xg0_k<<<256, 256, 0, stream>>>(node_rep, clique_idx, xb0);

    // ---- sequential loop: one persistent kernel, manual device barriers ----
    if (tu)
        loop_k<true><<<NBLK, 256, 0, stream>>>(
            nei_h_idx, node_rep, clique_idx, W_z_w, W_z_b, W_h_w, W_h_b,
            U_r_w, W_r_w, W_r_b, table, tu, hU,
            xb0, xb1, xrb, sumh, sumg, barcnt);
    else
        loop_k<false><<<NBLK, 256, 0, stream>>>(
            nei_h_idx, node_rep, clique_idx, W_z_w, W_z_b, W_h_w, W_h_b,
            U_r_w, W_r_w, W_r_b, table, tu, hU,
            xb0, xb1, xrb, sumh, sumg, barcnt);

    // ---- heads ----
    if (tu) {
        // o_all into tableU region (dead after loop)
        oall_k<<<BT * H / 4 / 256, 256, 0, stream>>>(nei_o_idx, table, tu);
        gemm_g<3, 2, 4><<<dim3((BT + B) / 64, 8), 256, SM_STOP, stream>>>(
            nullptr, tu, 0, U_w, U_b, nullptr, 0,
            node_rep, clique_idx, root_clique_idx, root_nei_idx,
            nullptr, table, U_s_w, partial);
    } else {
        gemm_g<7, 2, 4><<<dim3((BT + B) / 64, 8), 256, SM_STOP, stream>>>(
            nullptr, nullptr, 0, U_w, U_b, nullptr, 0,
            node_rep, clique_idx, root_clique_idx, root_nei_idx,
            nei_o_idx, table, U_s_w, partial);
    }
    stopfin_kernel<<<(BT + B) / 256, 256, 0, stream>>>(partial, U_s_b, direction, accum);

    if (tu) {
        // s1 = relu(h_all @ W_w + b) into tableU region (o_all dead now)
        gemm_g<0, 1, 3><<<dim3(BT / 64, 8), 256, SM_GEMM, stream>>>(
            table + H, nullptr, H, W_w, W_b, tu, H,
            nullptr, nullptr, nullptr, nullptr, nullptr, nullptr, nullptr, nullptr);
        ce_kernel<<<BT / 32, 256, 0, stream>>>(tu, W_o_w, W_o_b,
                                               direction, pred_target, accum);
    } else {
        predhead_kernel<<<BT / PH_ROWS, 256, 0, stream>>>(table, W_w, W_b,
                                                          W_o_w, W_o_b,
                                                          direction, pred_target, accum);
    }

    finalize_kernel<<<1, 64, 0, stream>>>(accum, (float*)d_out);
}

// Round 10
// 21944.887 us; speedup vs baseline: 2.3100x; 2.3100x over previous
//
#include <hip/hip_runtime.h>
#include <math.h>

constexpr int B    = 512;
constexpr int T    = 64;
constexpr int H    = 512;
constexpr int V    = 780;
constexpr int N_AT = 40;
constexpr int KC   = 4;
constexpr int NB   = 8;
constexpr int BT   = B * T;      // 32768
constexpr int NMSG = BT + 1;     // 32769
constexpr int BH   = B * H;      // 262144
constexpr int NBLK = 256;        // persistent grid size (1 block/CU)

__device__ __forceinline__ float sigf(float x) { return 1.f / (1.f + expf(-x)); }

// Manual device-wide barrier, cache-op-minimal:
//  - ONE release fence (buffer_wbl2) before a RELAXED arrive
//  - RELAXED polls (no per-poll L2 invalidate!)  <-- round-9 bug fixed
//  - ONE acquire fence (buffer_inv) after exit
__device__ __forceinline__ void gbar(unsigned* cnt, unsigned& epoch)
{
    __syncthreads();
    if (threadIdx.x == 0) {
        epoch += NBLK;
        __builtin_amdgcn_fence(__ATOMIC_RELEASE, "agent");
        __hip_atomic_fetch_add(cnt, 1u, __ATOMIC_RELAXED, __HIP_MEMORY_SCOPE_AGENT);
        while (__hip_atomic_load(cnt, __ATOMIC_RELAXED, __HIP_MEMORY_SCOPE_AGENT) < epoch)
            __builtin_amdgcn_s_sleep(2);
        __builtin_amdgcn_fence(__ATOMIC_ACQUIRE, "agent");
    }
    __syncthreads();
}

// ===========================================================================
// Phase bodies (verified in rounds 8/9)
// ===========================================================================

// z/h dual GEMM, 128 blocks of 32x64 tiles. K=1024 (seg0 x, seg1 sumh/sumg).
// table[b*T+t+1] = (1-z)*sumh + z*tanh-preh
__device__ __forceinline__ void ph_zh(int t, int bx, int tid,
    float* As1, float* As2, float* W1s, float* W2s,
    const float* __restrict__ xb, const float* __restrict__ sumh,
    const float* __restrict__ sumg,
    const float* __restrict__ Wz, const float* __restrict__ bz,
    const float* __restrict__ Wh, const float* __restrict__ bh,
    float* __restrict__ table)
{
    const int rt = bx >> 3, ct = bx & 7, row0 = rt * 32, col0 = ct * 64;
    const int tm = tid >> 4, tn = tid & 15;
    const int ak = tid & 31, am0 = tid >> 5, wn = tid & 63, wk0 = tid >> 6;
    float az[2][4] = {}, ah[2][4] = {};

    // seg0: shared A = x
    for (int k0 = 0; k0 < H; k0 += 32) {
#pragma unroll
        for (int it = 0; it < 4; ++it) {
            const int m = am0 + it * 8;
            As1[ak * 38 + m] = xb[(size_t)(row0 + m) * H + k0 + ak];
        }
#pragma unroll
        for (int it = 0; it < 8; ++it) {
            const int kk = wk0 + it * 4;
            W1s[kk * 68 + wn] = Wz[(size_t)(k0 + kk) * H + col0 + wn];
            W2s[kk * 68 + wn] = Wh[(size_t)(k0 + kk) * H + col0 + wn];
        }
        __syncthreads();
#pragma unroll
        for (int kk = 0; kk < 32; ++kk) {
            const float a0 = As1[kk * 38 + tm * 2];
            const float a1 = As1[kk * 38 + tm * 2 + 1];
            float w1[4], w2[4];
            *(float4*)w1 = *(const float4*)&W1s[kk * 68 + tn * 4];
            *(float4*)w2 = *(const float4*)&W2s[kk * 68 + tn * 4];
#pragma unroll
            for (int j = 0; j < 4; ++j) {
                az[0][j] = fmaf(a0, w1[j], az[0][j]);
                az[1][j] = fmaf(a1, w1[j], az[1][j]);
                ah[0][j] = fmaf(a0, w2[j], ah[0][j]);
                ah[1][j] = fmaf(a1, w2[j], ah[1][j]);
            }
        }
        __syncthreads();
    }
    // seg1: A1 = sumh -> z, A2 = sumg -> h
    for (int k0 = 0; k0 < H; k0 += 32) {
#pragma unroll
        for (int it = 0; it < 4; ++it) {
            const int m = am0 + it * 8;
            As1[ak * 38 + m] = sumh[(size_t)(row0 + m) * H + k0 + ak];
            As2[ak * 38 + m] = sumg[(size_t)(row0 + m) * H + k0 + ak];
        }
#pragma unroll
        for (int it = 0; it < 8; ++it) {
            const int kk = wk0 + it * 4;
            W1s[kk * 68 + wn] = Wz[(size_t)(H + k0 + kk) * H + col0 + wn];
            W2s[kk * 68 + wn] = Wh[(size_t)(H + k0 + kk) * H + col0 + wn];
        }
        __syncthreads();
#pragma unroll
        for (int kk = 0; kk < 32; ++kk) {
            const float a10 = As1[kk * 38 + tm * 2];
            const float a11 = As1[kk * 38 + tm * 2 + 1];
            const float a20 = As2[kk * 38 + tm * 2];
            const float a21 = As2[kk * 38 + tm * 2 + 1];
            float w1[4], w2[4];
            *(float4*)w1 = *(const float4*)&W1s[kk * 68 + tn * 4];
            *(float4*)w2 = *(const float4*)&W2s[kk * 68 + tn * 4];
#pragma unroll
            for (int j = 0; j < 4; ++j) {
                az[0][j] = fmaf(a10, w1[j], az[0][j]);
                az[1][j] = fmaf(a11, w1[j], az[1][j]);
                ah[0][j] = fmaf(a20, w2[j], ah[0][j]);
                ah[1][j] = fmaf(a21, w2[j], ah[1][j]);
            }
        }
        __syncthreads();
    }
    // epilogue: GRU blend -> table row b*T+t+1
#pragma unroll
    for (int i = 0; i < 2; ++i) {
        const int b = row0 + tm * 2 + i;
        const float4 s4 = *(const float4*)&sumh[(size_t)b * H + col0 + tn * 4];
        const float sv[4] = {s4.x, s4.y, s4.z, s4.w};
        float out[4];
#pragma unroll
        for (int j = 0; j < 4; ++j) {
            const int c = col0 + tn * 4 + j;
            const float z  = sigf(az[i][j] + bz[c]);
            const float ph = tanhf(ah[i][j] + bh[c]);
            out[j] = (1.f - z) * sv[j] + z * ph;
        }
        *(float4*)&table[((size_t)b * T + t + 1) * H + col0 + tn * 4] = *(float4*)out;
    }
}

// Generic 32x64-tile GEMM over K=512.
// AS: 0 = A[m][k] plain | 1 = A/C row = (m*T + tpos) | 2 = masked table gather
template<int AS>
__device__ __forceinline__ void tile_g(int bx, int tid, float* As, float* Ws_,
    const float* __restrict__ Abase, int tpos,
    const int* __restrict__ nh, int tstep,
    const float* __restrict__ W, const float* __restrict__ bias,
    float* __restrict__ C)
{
    const int rt = bx >> 3, ct = bx & 7, row0 = rt * 32, col0 = ct * 64;
    const int tm = tid >> 4, tn = tid & 15;
    const int ak = tid & 31, am0 = tid >> 5, wn = tid & 63, wk0 = tid >> 6;
    float ac[2][4] = {};

    for (int k0 = 0; k0 < H; k0 += 32) {
#pragma unroll
        for (int it = 0; it < 4; ++it) {
            const int m = am0 + it * 8, gm = row0 + m;
            float v;
            if (AS == 0) {
                v = Abase[(size_t)gm * H + k0 + ak];
            } else if (AS == 1) {
                v = Abase[((size_t)gm * T + tpos) * H + k0 + ak];
            } else {
                const int b = gm >> 3, n = gm & 7;
                const int gi = nh[((size_t)b * T + tstep) * NB + n];
                v = (gi != 0 && ((gi - 1) & 63) == tstep)
                        ? 0.f : Abase[(size_t)gi * H + k0 + ak];
            }
            As[ak * 38 + m] = v;
        }
#pragma unroll
        for (int it = 0; it < 8; ++it) {
            const int kk = wk0 + it * 4;
            Ws_[kk * 68 + wn] = W[(size_t)(k0 + kk) * H + col0 + wn];
        }
        __syncthreads();
#pragma unroll
        for (int kk = 0; kk < 32; ++kk) {
            const float a0 = As[kk * 38 + tm * 2];
            const float a1 = As[kk * 38 + tm * 2 + 1];
            float w[4];
            *(float4*)w = *(const float4*)&Ws_[kk * 68 + tn * 4];
#pragma unroll
            for (int j = 0; j < 4; ++j) {
                ac[0][j] = fmaf(a0, w[j], ac[0][j]);
                ac[1][j] = fmaf(a1, w[j], ac[1][j]);
            }
        }
        __syncthreads();
    }
#pragma unroll
    for (int i = 0; i < 2; ++i) {
        const int gm = row0 + tm * 2 + i;
        float out[4];
#pragma unroll
        for (int j = 0; j < 4; ++j)
            out[j] = ac[i][j] + (bias ? bias[col0 + tn * 4 + j] : 0.f);
        float* dst = (AS == 1) ? &C[((size_t)gm * T + tpos) * H + col0 + tn * 4]
                               : &C[(size_t)gm * H + col0 + tn * 4];
        *(float4*)dst = *(float4*)out;
    }
}

// clique gather: xb[b][h4..] for step tg (one float4 unit)
__device__ __forceinline__ void ph_xgather(int tg, int unit,
    const float* __restrict__ node_rep, const int* __restrict__ cliq,
    float* __restrict__ xb)
{
    const int b = unit >> 7, h4 = (unit & 127) * 4;
    const int* ci = cliq + ((size_t)b * T + tg) * KC;
    float4 s = {0.f, 0.f, 0.f, 0.f};
#pragma unroll
    for (int j = 0; j < KC; ++j) {
        const float4 v = *(const float4*)&node_rep[((size_t)b * N_AT + ci[j]) * H + h4];
        s.x += v.x; s.y += v.y; s.z += v.z; s.w += v.w;
    }
    *(float4*)&xb[(size_t)b * H + h4] = s;
}

// masked sumh / sumg gathers for step tg
template<bool USETU>
__device__ __forceinline__ void ph_sums(int tg, int unit,
    const int* __restrict__ nh, const float* __restrict__ xr,
    const float* __restrict__ table, const float* __restrict__ tu,
    const float* __restrict__ hU,
    float* __restrict__ sumh, float* __restrict__ sumg)
{
    const int b = unit >> 7, h4 = (unit & 127) * 4;
    const int* hi = nh + ((size_t)b * T + tg) * NB;
    const float4 x4 = *(const float4*)&xr[(size_t)b * H + h4];
    float4 sh = {0.f, 0.f, 0.f, 0.f}, sg = {0.f, 0.f, 0.f, 0.f};
#pragma unroll
    for (int n = 0; n < NB; ++n) {
        const int idx = hi[n];
        float4 hv = {0.f, 0.f, 0.f, 0.f};
        if (!(idx != 0 && ((idx - 1) & 63) == tg))
            hv = *(const float4*)&table[(size_t)idx * H + h4];
        const float4 hu = USETU ? *(const float4*)&tu[(size_t)idx * H + h4]
                                : *(const float4*)&hU[((size_t)b * NB + n) * H + h4];
        sh.x += hv.x; sh.y += hv.y; sh.z += hv.z; sh.w += hv.w;
        sg.x += hv.x * sigf(x4.x + hu.x);
        sg.y += hv.y * sigf(x4.y + hu.y);
        sg.z += hv.z * sigf(x4.z + hu.z);
        sg.w += hv.w * sigf(x4.w + hu.w);
    }
    *(float4*)&sumh[(size_t)b * H + h4] = sh;
    *(float4*)&sumg[(size_t)b * H + h4] = sg;
}

// ===========================================================================
// Persistent loop: normal launch, 256 blocks x 256 threads, manual barriers
// ===========================================================================
template<bool USETU>
__global__ __launch_bounds__(256)
void loop_k(const int* __restrict__ nei_h, const float* __restrict__ node_rep,
            const int* __restrict__ cliq,
            const float* __restrict__ Wz, const float* __restrict__ bz,
            const float* __restrict__ Wh, const float* __restrict__ bh,
            const float* __restrict__ Ur, const float* __restrict__ Wr,
            const float* __restrict__ br,
            float* table, float* tu, float* hU,
            float* xb0, float* xb1, float* xrb, float* sumh, float* sumg,
            unsigned* barcnt)
{
    __shared__ float As1[32 * 38], As2[32 * 38], W1s[32 * 68], W2s[32 * 68];
    const int bid = blockIdx.x, tid = threadIdx.x;
    unsigned epoch = 0;

    for (int t = 0; t < T; ++t) {
        float* xbc = (t & 1) ? xb1 : xb0;
        float* xbn = (t & 1) ? xb0 : xb1;
        // Phase A: z/h GEMM(t)  ||  x gather(t+1)
        if (bid < 128) {
            ph_zh(t, bid, tid, As1, As2, W1s, W2s, xbc, sumh, sumg,
                  Wz, bz, Wh, bh, table);
        } else if (t + 1 < T) {
            const int base = (bid - 128) * 512 + tid;
            ph_xgather(t + 1, base,       node_rep, cliq, xbn);
            ph_xgather(t + 1, base + 256, node_rep, cliq, xbn);
        }
        if (t + 1 == T) break;
        gbar(barcnt, epoch);
        // Phase B: tableU(t+1) (or hU(t+1))  ||  xr GEMM(t+1)
        if (USETU) {
            if (bid < 128)
                tile_g<1>(bid, tid, As1, W1s, table, t + 1, nullptr, 0,
                          Ur, nullptr, tu);
            else
                tile_g<0>(bid - 128, tid, As1, W1s, xbn, 0, nullptr, 0,
                          Wr, br, xrb);
        } else {
#pragma unroll
            for (int q = 0; q < 4; ++q)
                tile_g<2>(bid * 4 + q, tid, As1, W1s, table, 0, nei_h, t + 1,
                          Ur, nullptr, hU);
            if (bid < 128)
                tile_g<0>(bid, tid, As1, W1s, xbn, 0, nullptr, 0, Wr, br, xrb);
        }
        gbar(barcnt, epoch);
        // Phase C: masked sums(t+1)
        ph_sums<USETU>(t + 1, bid * 256 + tid, nei_h, xrb, table, tu, hU,
                       sumh, sumg);
        gbar(barcnt, epoch);
    }
}

// pre-loop x gather for t=0
__global__ __launch_bounds__(256)
void xg0_k(const float* __restrict__ node_rep, const int* __restrict__ cliq,
           float* __restrict__ xb)
{
    ph_xgather(0, blockIdx.x * 256 + threadIdx.x, node_rep, cliq, xb);
}

// ===========================================================================
// Post-loop: o_all from FINAL table with step mask ((idx-1)&63 < t)
// ===========================================================================
__global__ __launch_bounds__(256)
void oall_k(const int* __restrict__ nei_o, const float* __restrict__ table,
            float* __restrict__ o_all)
{
    const int i = blockIdx.x * 256 + threadIdx.x;   // BT*H/4
    const int m = i >> 7, h4 = (i & 127) * 4;       // m = b*T + t
    const int t = m & 63;
    const int* oi = nei_o + (size_t)m * NB;
    float4 s = {0.f, 0.f, 0.f, 0.f};
#pragma unroll
    for (int n = 0; n < NB; ++n) {
        const int idx = oi[n];
        if (idx != 0 && ((idx - 1) & 63) < t) {
            const float4 hv = *(const float4*)&table[(size_t)idx * H + h4];
            s.x += hv.x; s.y += hv.y; s.z += hv.z; s.w += hv.w;
        }
    }
    *(float4*)&o_all[(size_t)m * H + h4] = s;
}

// ===========================================================================
// Heads (verified rounds 8/9)
// ASRC: 0 plain | 3 stop (A2=o_all) | 7 stop (inline masked-o from table)
// EPI: 3 relu | 4 relu*Usw partial
// ===========================================================================
constexpr size_t SM_GEMM = (size_t)(2 * 32 * 68) * 4;
constexpr size_t SM_STOP = (size_t)(2 * 32 * 68 + 64 * 17) * 4;

template<int ASRC, int NSEG, int EPI>
__global__ __launch_bounds__(256)
void gemm_g(const float* __restrict__ A1, const float* __restrict__ A2, int lda,
            const float* __restrict__ W, const float* __restrict__ bias,
            float* __restrict__ C, int ldc,
            const float* __restrict__ node_rep, const int* __restrict__ cliq,
            const int* __restrict__ rci, const int* __restrict__ rni,
            const int* __restrict__ neio, const float* __restrict__ table,
            const float* __restrict__ Usw, float* __restrict__ partial)
{
    extern __shared__ float smem[];
    float* As = smem;
    float* Ws = smem + 32 * 68;
    const int tid = threadIdx.x, row0 = blockIdx.x * 64, col0 = blockIdx.y * 64;
    const int tm = tid >> 4, tn = tid & 15;
    const int ar0 = tid >> 5, ac = tid & 31, wk0 = tid >> 6, wc = tid & 63;
    float acc[4][4] = {};

    for (int seg = 0; seg < NSEG; ++seg) {
        const float* Wseg = W + (size_t)seg * H * H;
        for (int k0 = 0; k0 < H; k0 += 32) {
#pragma unroll
            for (int it = 0; it < 8; ++it) {
                const int r = ar0 + it * 8, grow = row0 + r;
                float v;
                if (ASRC == 0) {
                    v = A1[(size_t)grow * lda + k0 + ac];
                } else {
                    if (grow < BT) {
                        if (seg == 0) {
                            const int* ci = cliq + (size_t)grow * KC;
                            const int b = grow >> 6;
                            v = 0.f;
#pragma unroll
                            for (int j = 0; j < KC; ++j)
                                v += node_rep[((size_t)b * N_AT + ci[j]) * H + k0 + ac];
                        } else if (ASRC == 3) {
                            v = A2[(size_t)grow * H + k0 + ac];
                        } else {  // ASRC == 7: inline masked o
                            const int tt = grow & 63;
                            const int* oi = neio + (size_t)grow * NB;
                            v = 0.f;
#pragma unroll
                            for (int n = 0; n < NB; ++n) {
                                const int idx = oi[n];
                                if (idx != 0 && ((idx - 1) & 63) < tt)
                                    v += table[(size_t)idx * H + k0 + ac];
                            }
                        }
                    } else {
                        const int b = grow - BT;
                        v = 0.f;
                        if (seg == 0) {
#pragma unroll
                            for (int j = 0; j < KC; ++j)
                                v += node_rep[((size_t)b * N_AT + rci[b * KC + j]) * H + k0 + ac];
                        } else {
#pragma unroll
                            for (int n = 0; n < NB; ++n)
                                v += table[(size_t)rni[b * NB + n] * H + k0 + ac];
                        }
                    }
                }
                As[(size_t)ac * 68 + r] = v;
                const int kk = wk0 + it * 4;
                Ws[(size_t)kk * 68 + wc] = Wseg[(size_t)(k0 + kk) * H + col0 + wc];
            }
            __syncthreads();
#pragma unroll
            for (int kk = 0; kk < 32; ++kk) {
                float a[4], w[4];
                *(float4*)a = *(const float4*)&As[kk * 68 + tm * 4];
                *(float4*)w = *(const float4*)&Ws[kk * 68 + tn * 4];
#pragma unroll
                for (int i = 0; i < 4; ++i)
#pragma unroll
                    for (int j = 0; j < 4; ++j)
                        acc[i][j] = fmaf(a[i], w[j], acc[i][j]);
            }
            __syncthreads();
        }
    }

    if (EPI == 4) {
        float* sred = smem + 2 * 32 * 68;   // [64][17]
#pragma unroll
        for (int i = 0; i < 4; ++i) {
            float s = 0.f;
#pragma unroll
            for (int j = 0; j < 4; ++j) {
                const int c = col0 + tn * 4 + j;
                s += fmaxf(acc[i][j] + bias[c], 0.f) * Usw[c];
            }
            sred[(size_t)(tm * 4 + i) * 17 + tn] = s;
        }
        __syncthreads();
        if (tid < 64) {
            float s = 0.f;
#pragma unroll
            for (int q = 0; q < 16; ++q) s += sred[(size_t)tid * 17 + q];
            partial[(size_t)(row0 + tid) * 8 + blockIdx.y] = s;
        }
    } else {
#pragma unroll
        for (int i = 0; i < 4; ++i) {
            const int r = row0 + tm * 4 + i;
            float out[4];
#pragma unroll
            for (int j = 0; j < 4; ++j) {
                float val = acc[i][j] + (bias ? bias[col0 + tn * 4 + j] : 0.f);
                if (EPI == 3) val = fmaxf(val, 0.f);
                out[j] = val;
            }
            *(float4*)&C[(size_t)r * ldc + col0 + tn * 4] = *(float4*)out;
        }
    }
}

__global__ __launch_bounds__(256)
void stopfin_kernel(const float* __restrict__ partial, const float* __restrict__ Usb,
                    const int* __restrict__ direction, float* __restrict__ accum)
{
    const int i = blockIdx.x * 256 + threadIdx.x;   // BT+B exactly
    float loss = 0.f, acc = 0.f;
    {
        float s = Usb[0];
#pragma unroll
        for (int cb = 0; cb < 8; ++cb) s += partial[(size_t)i * 8 + cb];
        const float tgt = (i < BT) ? (float)direction[i] : 0.f;
        loss = fmaxf(s, 0.f) - s * tgt + log1pf(expf(-fabsf(s)));
        const float p = (s >= 0.f) ? 1.f : 0.f;
        acc = (p == tgt) ? 1.f : 0.f;
    }
#pragma unroll
    for (int off = 32; off; off >>= 1) {
        loss += __shfl_down(loss, off);
        acc  += __shfl_down(acc, off);
    }
    if ((threadIdx.x & 63) == 0) {
        atomicAdd(&accum[3], loss);
        atomicAdd(&accum[4], acc);
    }
}

// pred head phase 2: fused scores GEMM + log-softmax CE + argmax (verified)
__global__ __launch_bounds__(256)
void ce_kernel(const float* __restrict__ s1_all, const float* __restrict__ Wo,
               const float* __restrict__ Wob, const int* __restrict__ direction,
               const int* __restrict__ ptgt, float* __restrict__ accum)
{
    __shared__ float s1T[512 * 34];
    __shared__ float Ws[32 * 68];
    __shared__ float blk[3];
    const int tid  = threadIdx.x;
    const int row0 = blockIdx.x * 32;

    for (int idx = tid; idx < 32 * 512; idx += 256) {
        const int r = idx >> 9, k = idx & 511;
        s1T[(size_t)k * 34 + r] = s1_all[(size_t)(row0 + r) * H + k];
    }
    if (tid < 3) blk[tid] = 0.f;
    __syncthreads();

    const int tm = tid >> 4, tn = tid & 15;
    const int tgt0 = ptgt[row0 + tm * 2];
    const int tgt1 = ptgt[row0 + tm * 2 + 1];
    float m0 = -1e30f, m1 = -1e30f, ss0 = 0.f, ss1 = 0.f, st0 = 0.f, st1 = 0.f;
    float bv0 = -1e30f, bv1 = -1e30f;
    int   bj0 = 0, bj1 = 0;

    for (int ct = 0; ct < 13; ++ct) {
        const int col0 = ct * 64;
        float acc[2][4] = {};
        for (int k0 = 0; k0 < 512; k0 += 32) {
#pragma unroll
            for (int it = 0; it < 8; ++it) {
                const int idx = tid + it * 256;
                const int kk = idx >> 6, cc = idx & 63;
                const int col = col0 + cc;
                Ws[(size_t)kk * 68 + cc] = (col < V) ? Wo[(size_t)(k0 + kk) * V + col] : 0.f;
            }
            __syncthreads();
#pragma unroll
            for (int kk = 0; kk < 32; ++kk) {
                const float a0 = s1T[(size_t)(k0 + kk) * 34 + tm * 2];
                const float a1 = s1T[(size_t)(k0 + kk) * 34 + tm * 2 + 1];
                float w[4];
                *(float4*)w = *(const float4*)&Ws[kk * 68 + tn * 4];
#pragma unroll
                for (int j = 0; j < 4; ++j) {
                    acc[0][j] = fmaf(a0, w[j], acc[0][j]);
                    acc[1][j] = fmaf(a1, w[j], acc[1][j]);
                }
            }
            __syncthreads();
        }
#pragma unroll
        for (int j = 0; j < 4; ++j) {
            const int col = col0 + tn * 4 + j;
            if (col < V) {
                const float wb  = Wob[col];
                const float sc0 = acc[0][j] + wb;
                const float sc1 = acc[1][j] + wb;
                if (sc0 > m0) { ss0 = ss0 * expf(m0 - sc0) + 1.f; m0 = sc0; }
                else          { ss0 += expf(sc0 - m0); }
                if (sc1 > m1) { ss1 = ss1 * expf(m1 - sc1) + 1.f; m1 = sc1; }
                else          { ss1 += expf(sc1 - m1); }
                if (sc0 > bv0) { bv0 = sc0; bj0 = col; }
                if (sc1 > bv1) { bv1 = sc1; bj1 = col; }
                if (col == tgt0) st0 = sc0;
                if (col == tgt1) st1 = sc1;
            }
        }
    }

#pragma unroll
    for (int off = 1; off < 16; off <<= 1) {
        float om, os;
        om = __shfl_xor(m0, off); os = __shfl_xor(ss0, off);
        { const float nm = fmaxf(m0, om); ss0 = ss0 * expf(m0 - nm) + os * expf(om - nm); m0 = nm; }
        om = __shfl_xor(m1, off); os = __shfl_xor(ss1, off);
        { const float nm = fmaxf(m1, om); ss1 = ss1 * expf(m1 - nm) + os * expf(om - nm); m1 = nm; }
        float obv; int obj;
        obv = __shfl_xor(bv0, off); obj = __shfl_xor(bj0, off);
        if (obv > bv0 || (obv == bv0 && obj < bj0)) { bv0 = obv; bj0 = obj; }
        obv = __shfl_xor(bv1, off); obj = __shfl_xor(bj1, off);
        if (obv > bv1 || (obv == bv1 && obj < bj1)) { bv1 = obv; bj1 = obj; }
        st0 += __shfl_xor(st0, off);
        st1 += __shfl_xor(st1, off);
    }
    if (tn == 0) {
        float ce_s = 0.f, cnt = 0.f, corr = 0.f;
        {
            const int row = row0 + tm * 2;
            if (direction[row] == 1) {
                ce_s += (m0 + logf(ss0)) - st0; cnt += 1.f;
                corr += (bj0 == tgt0) ? 1.f : 0.f;
            }
        }
        {
            const int row = row0 + tm * 2 + 1;
            if (direction[row] == 1) {
                ce_s += (m1 + logf(ss1)) - st1; cnt += 1.f;
                corr += (bj1 == tgt1) ? 1.f : 0.f;
            }
        }
        atomicAdd(&blk[0], ce_s); atomicAdd(&blk[1], cnt); atomicAdd(&blk[2], corr);
    }
    __syncthreads();
    if (tid == 0) {
        atomicAdd(&accum[0], blk[0]);
        atomicAdd(&accum[1], blk[1]);
        atomicAdd(&accum[2], blk[2]);
    }
}

// no-tableU fallback pred head (round-0 proven; reads table directly)
constexpr int PH_ROWS = 8;
__global__ __launch_bounds__(256)
void predhead_kernel(const float* __restrict__ table,
                     const float* __restrict__ Ww, const float* __restrict__ Wb,
                     const float* __restrict__ Wo, const float* __restrict__ Wob,
                     const int* __restrict__ direction, const int* __restrict__ ptgt,
                     float* __restrict__ accum)
{
    __shared__ float hs[PH_ROWS][520];
    __shared__ float s1s[PH_ROWS][520];
    const int row0 = blockIdx.x * PH_ROWS;
    const int tid  = threadIdx.x;
    for (int i = tid; i < PH_ROWS * H; i += 256) {
        const int r = i >> 9, c = i & 511;
        hs[r][c] = table[(size_t)(row0 + r + 1) * H + c];
    }
    __syncthreads();
    const int r  = tid >> 5;
    const int tx = tid & 31;
    for (int j = 0; j < 16; ++j) {
        const int c = tx + j * 32;
        float acc = Wb[c];
        for (int k = 0; k < H; ++k) acc += hs[r][k] * Ww[(size_t)k * H + c];
        s1s[r][c] = fmaxf(acc, 0.f);
    }
    __syncthreads();
    const int row = row0 + r;
    const int tgt = ptgt[row];
    float m = -1e30f, ssum = 0.f, stgt = 0.f;
    float bestv = -1e30f; int bestj = 0;
    for (int v = tx; v < V; v += 32) {
        float sc = Wob[v];
        const float* wcol = Wo + v;
        for (int k = 0; k < H; ++k) sc += s1s[r][k] * wcol[(size_t)k * V];
        if (sc > m) { ssum = ssum * expf(m - sc) + 1.f; m = sc; }
        else        { ssum += expf(sc - m); }
        if (sc > bestv) { bestv = sc; bestj = v; }
        if (v == tgt) stgt = sc;
    }
#pragma unroll
    for (int off = 1; off < 32; off <<= 1) {
        const float om = __shfl_xor(m, off);
        const float os = __shfl_xor(ssum, off);
        const float nm = fmaxf(m, om);
        ssum = ssum * expf(m - nm) + os * expf(om - nm);
        m = nm;
        const float obv = __shfl_xor(bestv, off);
        const int   obj = __shfl_xor(bestj, off);
        if (obv > bestv || (obv == bestv && obj < bestj)) { bestv = obv; bestj = obj; }
        stgt += __shfl_xor(stgt, off);
    }
    if (tx == 0) {
        const float ce   = (m + logf(ssum)) - stgt;
        const float mask = (direction[row] == 1) ? 1.f : 0.f;
        const float corr = (bestj == tgt) ? 1.f : 0.f;
        atomicAdd(&accum[0], ce * mask);
        atomicAdd(&accum[1], mask);
        atomicAdd(&accum[2], corr * mask);
    }
}

__global__ void finalize_kernel(const float* __restrict__ accum, float* __restrict__ out)
{
    if (threadIdx.x == 0) {
        out[0] = accum[0] / (float)B;
        out[1] = accum[3] / (float)B;
        out[2] = accum[2] / accum[1];
        out[3] = accum[4] / (float)(BT + B);
    }
}

// ===========================================================================
extern "C" void kernel_launch(void* const* d_in, const int* in_sizes, int n_in,
                              void* d_out, int out_size, void* d_ws, size_t ws_size,
                              hipStream_t stream)
{
    (void)in_sizes; (void)n_in; (void)out_size;

    const float* node_rep        = (const float*)d_in[0];
    const int*   clique_idx      = (const int*)d_in[1];
    const int*   root_clique_idx = (const int*)d_in[2];
    const int*   nei_h_idx       = (const int*)d_in[3];
    const int*   nei_o_idx       = (const int*)d_in[4];
    const int*   root_nei_idx    = (const int*)d_in[5];
    const int*   direction       = (const int*)d_in[6];
    const int*   pred_target     = (const int*)d_in[7];
    const float* W_z_w = (const float*)d_in[8];
    const float* W_z_b = (const float*)d_in[9];
    const float* W_r_w = (const float*)d_in[10];
    const float* W_r_b = (const float*)d_in[11];
    const float* U_r_w = (const float*)d_in[12];
    const float* W_h_w = (const float*)d_in[13];
    const float* W_h_b = (const float*)d_in[14];
    const float* W_w   = (const float*)d_in[15];
    const float* W_b   = (const float*)d_in[16];
    const float* U_w   = (const float*)d_in[17];
    const float* U_b   = (const float*)d_in[18];
    const float* W_o_w = (const float*)d_in[19];
    const float* W_o_b = (const float*)d_in[20];
    const float* U_s_w = (const float*)d_in[21];
    const float* U_s_b = (const float*)d_in[22];

    float* ws = (float*)d_ws;
    const size_t availF = ws_size / sizeof(float);
    size_t off = 0;
    auto alloc = [&](size_t n) { float* p = ws + off; off += n; return p; };

    float* table   = alloc((size_t)NMSG * H);
    float* xb0     = alloc(BH);
    float* xb1     = alloc(BH);
    float* xrb     = alloc(BH);
    float* sumh    = alloc(BH);
    float* sumg    = alloc(BH);
    float* partial = alloc((size_t)(BT + B) * 8);
    float* accum   = alloc(16);                 // [0..7] accum, [8] barrier cnt
    unsigned* barcnt = (unsigned*)(accum + 8);

    // gate the 67 MB tableU on actual ws capacity (proven: ws >= 152.3 MB)
    float* tu = nullptr;
    float* hU = nullptr;
    if (off + (size_t)NMSG * H <= availF) tu = alloc((size_t)NMSG * H);
    else                                  hU = alloc((size_t)B * NB * H);

    hipMemsetAsync(table, 0, (size_t)NMSG * H * sizeof(float), stream);
    if (tu) hipMemsetAsync(tu, 0, (size_t)NMSG * H * sizeof(float), stream);
    hipMemsetAsync(sumh, 0, (size_t)BH * sizeof(float), stream);
    hipMemsetAsync(sumg, 0, (size_t)BH * sizeof(float), stream);
    hipMemsetAsync(accum, 0, 16 * sizeof(float), stream);

    // pre-loop: x for t=0
    xg0_k<<<256, 256, 0, stream>>>(node_rep, clique_idx, xb0);

    // ---- sequential loop: one persistent kernel, manual device barriers ----
    if (tu)
        loop_k<true><<<NBLK, 256, 0, stream>>>(
            nei_h_idx, node_rep, clique_idx, W_z_w, W_z_b, W_h_w, W_h_b,
            U_r_w, W_r_w, W_r_b, table, tu, hU,
            xb0, xb1, xrb, sumh, sumg, barcnt);
    else
        loop_k<false><<<NBLK, 256, 0, stream>>>(
            nei_h_idx, node_rep, clique_idx, W_z_w, W_z_b, W_h_w, W_h_b,
            U_r_w, W_r_w, W_r_b, table, tu, hU,
            xb0, xb1, xrb, sumh, sumg, barcnt);

    // ---- heads ----
    if (tu) {
        // o_all into tableU region (dead after loop)
        oall_k<<<BT * H / 4 / 256, 256, 0, stream>>>(nei_o_idx, table, tu);
        gemm_g<3, 2, 4><<<dim3((BT + B) / 64, 8), 256, SM_STOP, stream>>>(
            nullptr, tu, 0, U_w, U_b, nullptr, 0,
            node_rep, clique_idx, root_clique_idx, root_nei_idx,
            nullptr, table, U_s_w, partial);
    } else {
        gemm_g<7, 2, 4><<<dim3((BT + B) / 64, 8), 256, SM_STOP, stream>>>(
            nullptr, nullptr, 0, U_w, U_b, nullptr, 0,
            node_rep, clique_idx, root_clique_idx, root_nei_idx,
            nei_o_idx, table, U_s_w, partial);
    }
    stopfin_kernel<<<(BT + B) / 256, 256, 0, stream>>>(partial, U_s_b, direction, accum);

    if (tu) {
        // s1 = relu(h_all @ W_w + b) into tableU region (o_all dead now)
        gemm_g<0, 1, 3><<<dim3(BT / 64, 8), 256, SM_GEMM, stream>>>(
            table + H, nullptr, H, W_w, W_b, tu, H,
            nullptr, nullptr, nullptr, nullptr, nullptr, nullptr, nullptr, nullptr);
        ce_kernel<<<BT / 32, 256, 0, stream>>>(tu, W_o_w, W_o_b,
                                               direction, pred_target, accum);
    } else {
        predhead_kernel<<<BT / PH_ROWS, 256, 0, stream>>>(table, W_w, W_b,
                                                          W_o_w, W_o_b,
                                                          direction, pred_target, accum);
    }

    finalize_kernel<<<1, 64, 0, stream>>>(accum, (float*)d_out);
}